// Round 2
// baseline (215.043 us; speedup 1.0000x reference)
//
#include <hip/hip_runtime.h>
#include <hip/hip_bf16.h>

typedef __attribute__((ext_vector_type(8)))  __bf16 bf16x8;
typedef __attribute__((ext_vector_type(16))) float  f32x16;

// Batched GEMM C[b] = A[b] @ B[b]^T, A:[B,N1,D] B:[B,N2,D] C:[B,N1,N2], D=64.
// Write-bound: 536 MB out vs 32 MB in. bf16 MFMA (no fp32 MFMA on CDNA4).
// Key tricks:
//  - swapped MFMA operands: mfma(B_frag, A_frag) yields C^T-layout tile, so
//    each lane's acc quads are 4 CONSECUTIVE C columns -> dwordx4 stores.
//  - bijective XCD chunk swizzle: XCD k gets batch k (4 MB inputs == one L2).
//  - A fragments hoisted to registers; per-cb acc (32 VGPR live, not 64).

static __device__ inline bf16x8 to_bf16x8(const float4& a, const float4& b) {
    bf16x8 r;
    r[0] = (__bf16)a.x; r[1] = (__bf16)a.y; r[2] = (__bf16)a.z; r[3] = (__bf16)a.w;
    r[4] = (__bf16)b.x; r[5] = (__bf16)b.y; r[6] = (__bf16)b.z; r[7] = (__bf16)b.w;
    return r;
}

__global__ __launch_bounds__(256) void MatrixAttention_76149770158251_kernel(
    const float* __restrict__ A, const float* __restrict__ Bm,
    float* __restrict__ C, int N1, int N2, int D)
{
    // ---- XCD-aware bijective swizzle: consecutive-dispatch blocks (which the
    // HW round-robins across XCDs) decode to DIFFERENT batches; XCD k ends up
    // owning batch k, whose 4 MB of inputs fit its private L2 exactly.
    const int GX = 32, GY = 32;             // gridDim.x, gridDim.y
    const int NXCD = 8;
    int lin = blockIdx.x + GX * (blockIdx.y + GY * blockIdx.z);
    const int nwg = GX * GY * 8;            // 8192, divisible by 8
    const int cpx = nwg / NXCD;             // 1024
    int swz = (lin % NXCD) * cpx + lin / NXCD;
    const int bx = swz % GX;
    const int by = (swz / GX) % GY;
    const int bz = swz / (GX * GY);

    const int lane = threadIdx.x & 63;
    const int wid  = threadIdx.x >> 6;      // 0..3
    const int wr   = wid >> 1;              // 2x2 wave grid
    const int wc   = wid & 1;

    const int row0 = by * 128 + wr * 64;
    const int col0 = bx * 128 + wc * 64;

    const float* __restrict__ Ab = A  + (size_t)bz * N1 * D;
    const float* __restrict__ Bb = Bm + (size_t)bz * N2 * D;
    float* __restrict__ Cb       = C  + (size_t)bz * N1 * N2;

    const int lrow  = lane & 31;            // matrix row within 32-frag
    const int khalf = (lane >> 5) * 8;      // 0 or 8: which 8-elem K slice

    // ---- hoist all A fragments (2 row-blocks x 4 K-steps) into registers
    bf16x8 af[2][4];
#pragma unroll
    for (int rb = 0; rb < 2; ++rb)
#pragma unroll
        for (int ks = 0; ks < 4; ++ks) {
            const float* p = Ab + (size_t)(row0 + rb * 32 + lrow) * D + ks * 16 + khalf;
            float4 v0 = *(const float4*)(p);
            float4 v1 = *(const float4*)(p + 4);
            af[rb][ks] = to_bf16x8(v0, v1);
        }

    // ---- per column-block: load B frags, MFMA (swapped operands), wide store
#pragma unroll
    for (int cb = 0; cb < 2; ++cb) {
        f32x16 acc0 = (f32x16)0.0f;         // rb = 0
        f32x16 acc1 = (f32x16)0.0f;         // rb = 1
#pragma unroll
        for (int ks = 0; ks < 4; ++ks) {
            const float* p = Bb + (size_t)(col0 + cb * 32 + lrow) * D + ks * 16 + khalf;
            float4 v0 = *(const float4*)(p);
            float4 v1 = *(const float4*)(p + 4);
            bf16x8 bfr = to_bf16x8(v0, v1);
            // SWAPPED: first operand = B fragment -> D = C^T sub-tile:
            //   C row i = lane&31,  C col j = (v&3) + 8*(v>>2) + 4*(lane>>5)
            acc0 = __builtin_amdgcn_mfma_f32_32x32x16_bf16(bfr, af[0][ks], acc0, 0, 0, 0);
            acc1 = __builtin_amdgcn_mfma_f32_32x32x16_bf16(bfr, af[1][ks], acc1, 0, 0, 0);
        }
        // stores: acc quads [4g..4g+3] are consecutive C columns of one row
        const int jbase = col0 + cb * 32 + 4 * (lane >> 5);
        {
            const size_t r0 = (size_t)(row0 + 0 * 32 + (lane & 31)) * N2;
            const size_t r1 = (size_t)(row0 + 1 * 32 + (lane & 31)) * N2;
#pragma unroll
            for (int g = 0; g < 4; ++g) {
                float4 s0 = make_float4(acc0[4*g+0], acc0[4*g+1], acc0[4*g+2], acc0[4*g+3]);
                float4 s1 = make_float4(acc1[4*g+0], acc1[4*g+1], acc1[4*g+2], acc1[4*g+3]);
                *(float4*)(Cb + r0 + jbase + 8 * g) = s0;
                *(float4*)(Cb + r1 + jbase + 8 * g) = s1;
            }
        }
    }
}

extern "C" void kernel_launch(void* const* d_in, const int* in_sizes, int n_in,
                              void* d_out, int out_size, void* d_ws, size_t ws_size,
                              hipStream_t stream) {
    const float* m1 = (const float*)d_in[0];
    const float* m2 = (const float*)d_in[1];
    float* out = (float*)d_out;

    const int N1 = 4096, N2 = 4096, D = 64;
    dim3 grid(N2 / 128, N1 / 128, 8);
    dim3 block(256);
    MatrixAttention_76149770158251_kernel<<<grid, block, 0, stream>>>(m1, m2, out, N1, N2, D);
}

// Round 3
// 183.906 us; speedup vs baseline: 1.1693x; 1.1693x over previous
//
#include <hip/hip_runtime.h>
#include <hip/hip_bf16.h>

typedef __attribute__((ext_vector_type(8)))  __bf16 bf16x8;
typedef __attribute__((ext_vector_type(16))) float  f32x16;

// Batched GEMM C[b] = A[b] @ B[b]^T, A:[B,N1,D] B:[B,N2,D] C:[B,N1,N2], D=64.
// Write-bound: 536 MB out, 32 MB in (inputs L3-resident -> reads ~free).
// Round-3 lever: epilogue LDS staging so global stores are fillBuffer-shaped
// (each wave inst = 1 KB covering whole 128B/256B sectors -> no read-for-
// ownership fetch of the poisoned output lines). Compute identical to round 1.

static __device__ inline bf16x8 to_bf16x8(const float4& a, const float4& b) {
    bf16x8 r;
    r[0] = (__bf16)a.x; r[1] = (__bf16)a.y; r[2] = (__bf16)a.z; r[3] = (__bf16)a.w;
    r[4] = (__bf16)b.x; r[5] = (__bf16)b.y; r[6] = (__bf16)b.z; r[7] = (__bf16)b.w;
    return r;
}

__global__ __launch_bounds__(256) void MatrixAttention_76149770158251_kernel(
    const float* __restrict__ A, const float* __restrict__ Bm,
    float* __restrict__ C, int N1, int N2, int D)
{
    __shared__ float tile[128 * 128];       // 64 KB C-tile staging

    const int lane = threadIdx.x & 63;
    const int wid  = threadIdx.x >> 6;      // 0..3
    const int wr   = wid >> 1;              // 2x2 wave grid
    const int wc   = wid & 1;
    const int b    = blockIdx.z;

    const int brow = blockIdx.y * 128;
    const int bcol = blockIdx.x * 128;
    const int row0 = brow + wr * 64;
    const int col0 = bcol + wc * 64;

    const float* __restrict__ Ab = A  + (size_t)b * N1 * D;
    const float* __restrict__ Bb = Bm + (size_t)b * N2 * D;
    float* __restrict__ Cb       = C  + (size_t)b * N1 * N2;

    const int lrow  = lane & 31;            // row within 32-frag
    const int khalf = (lane >> 5) * 8;      // 0 or 8: K slice

    f32x16 acc[2][2];
#pragma unroll
    for (int i = 0; i < 2; ++i)
#pragma unroll
        for (int j = 0; j < 2; ++j) acc[i][j] = (f32x16)0.0f;

#pragma unroll
    for (int ks = 0; ks < 4; ++ks) {        // K = 64 = 4 * 16
        const int k = ks * 16 + khalf;
        bf16x8 af[2], bfr[2];
#pragma unroll
        for (int rb = 0; rb < 2; ++rb) {
            const float* p = Ab + (size_t)(row0 + rb * 32 + lrow) * D + k;
            float4 v0 = *(const float4*)(p);
            float4 v1 = *(const float4*)(p + 4);
            af[rb] = to_bf16x8(v0, v1);
        }
#pragma unroll
        for (int cb = 0; cb < 2; ++cb) {
            const float* p = Bb + (size_t)(col0 + cb * 32 + lrow) * D + k;
            float4 v0 = *(const float4*)(p);
            float4 v1 = *(const float4*)(p + 4);
            bfr[cb] = to_bf16x8(v0, v1);
        }
#pragma unroll
        for (int rb = 0; rb < 2; ++rb)
#pragma unroll
            for (int cb = 0; cb < 2; ++cb)
                acc[rb][cb] = __builtin_amdgcn_mfma_f32_32x32x16_bf16(
                    af[rb], bfr[cb], acc[rb][cb], 0, 0, 0);
    }

    // ---- stage acc -> LDS in block-tile coordinates
    // D layout (verified): col = lane&31, row = (v&3) + 8*(v>>2) + 4*(lane>>5)
#pragma unroll
    for (int rb = 0; rb < 2; ++rb)
#pragma unroll
        for (int cb = 0; cb < 2; ++cb) {
            const int col   = wc * 64 + cb * 32 + (lane & 31);
            const int rbase = wr * 64 + rb * 32 + 4 * (lane >> 5);
#pragma unroll
            for (int v = 0; v < 16; ++v) {
                const int r = rbase + (v & 3) + 8 * (v >> 2);
                tile[r * 128 + col] = acc[rb][cb][v];
            }
        }

    __syncthreads();

    // ---- fillBuffer-shaped store sweep: lane i writes 16B at linear
    // offset i*16; each wave inst covers 2 complete 512B-aligned C rows.
    const float4* t4 = (const float4*)tile;
    float* Cbase = Cb + (size_t)brow * N2 + bcol;
#pragma unroll
    for (int it = 0; it < 16; ++it) {
        const int f  = it * 256 + threadIdx.x;   // float4 index in tile
        const int r  = f >> 5;                   // 32 float4 per 128-col row
        const int cq = f & 31;
        *(float4*)(Cbase + (size_t)r * N2 + cq * 4) = t4[f];
    }
}

extern "C" void kernel_launch(void* const* d_in, const int* in_sizes, int n_in,
                              void* d_out, int out_size, void* d_ws, size_t ws_size,
                              hipStream_t stream) {
    const float* m1 = (const float*)d_in[0];
    const float* m2 = (const float*)d_in[1];
    float* out = (float*)d_out;

    const int N1 = 4096, N2 = 4096, D = 64;
    dim3 grid(N2 / 128, N1 / 128, 8);
    dim3 block(256);
    MatrixAttention_76149770158251_kernel<<<grid, block, 0, stream>>>(m1, m2, out, N1, N2, D);
}

// Round 5
// 154.655 us; speedup vs baseline: 1.3905x; 1.1891x over previous
//
#include <hip/hip_runtime.h>
#include <hip/hip_bf16.h>

typedef __attribute__((ext_vector_type(8)))  __bf16 bf16x8;
typedef __attribute__((ext_vector_type(16))) float  f32x16;
typedef __attribute__((ext_vector_type(4)))  float  f32x4;   // for nt stores

// Batched GEMM C[b] = A[b] @ B[b]^T, A:[B,N1,D] B:[B,N2,D] C:[B,N1,N2], D=64.
// Write-bound: 536 MB out (2x the 256 MiB L3!), 32 MB in.
// Lever under test: NON-TEMPORAL C stores. Cached stores allocate in L2/L3;
// the 536 MB stream overflows L3 so every line is allocated AND dirty-evicted
// (2x fabric crossings -> observed ~2.9 TB/s ceiling, rounds 1-3). nt stores
// bypass allocation and should stream at memset rate (~6.7 TB/s observed).

static __device__ inline bf16x8 to_bf16x8(const float4& a, const float4& b) {
    bf16x8 r;
    r[0] = (__bf16)a.x; r[1] = (__bf16)a.y; r[2] = (__bf16)a.z; r[3] = (__bf16)a.w;
    r[4] = (__bf16)b.x; r[5] = (__bf16)b.y; r[6] = (__bf16)b.z; r[7] = (__bf16)b.w;
    return r;
}

__global__ __launch_bounds__(256) void MatrixAttention_76149770158251_kernel(
    const float* __restrict__ A, const float* __restrict__ Bm,
    float* __restrict__ C, int N1, int N2, int D)
{
    __shared__ float tile[128 * 128];       // 64 KB C-tile staging

    const int lane = threadIdx.x & 63;
    const int wid  = threadIdx.x >> 6;      // 0..3
    const int wr   = wid >> 1;              // 2x2 wave grid
    const int wc   = wid & 1;
    const int b    = blockIdx.z;

    const int brow = blockIdx.y * 128;
    const int bcol = blockIdx.x * 128;
    const int row0 = brow + wr * 64;
    const int col0 = bcol + wc * 64;

    const float* __restrict__ Ab = A  + (size_t)b * N1 * D;
    const float* __restrict__ Bb = Bm + (size_t)b * N2 * D;
    float* __restrict__ Cb       = C  + (size_t)b * N1 * N2;

    const int lrow  = lane & 31;            // row within 32-frag
    const int khalf = (lane >> 5) * 8;      // 0 or 8: K slice

    f32x16 acc[2][2];
#pragma unroll
    for (int i = 0; i < 2; ++i)
#pragma unroll
        for (int j = 0; j < 2; ++j) acc[i][j] = (f32x16)0.0f;

#pragma unroll
    for (int ks = 0; ks < 4; ++ks) {        // K = 64 = 4 * 16
        const int k = ks * 16 + khalf;
        bf16x8 af[2], bfr[2];
#pragma unroll
        for (int rb = 0; rb < 2; ++rb) {
            const float* p = Ab + (size_t)(row0 + rb * 32 + lrow) * D + k;
            float4 v0 = *(const float4*)(p);
            float4 v1 = *(const float4*)(p + 4);
            af[rb] = to_bf16x8(v0, v1);
        }
#pragma unroll
        for (int cb = 0; cb < 2; ++cb) {
            const float* p = Bb + (size_t)(col0 + cb * 32 + lrow) * D + k;
            float4 v0 = *(const float4*)(p);
            float4 v1 = *(const float4*)(p + 4);
            bfr[cb] = to_bf16x8(v0, v1);
        }
#pragma unroll
        for (int rb = 0; rb < 2; ++rb)
#pragma unroll
            for (int cb = 0; cb < 2; ++cb)
                acc[rb][cb] = __builtin_amdgcn_mfma_f32_32x32x16_bf16(
                    af[rb], bfr[cb], acc[rb][cb], 0, 0, 0);
    }

    // ---- stage acc -> LDS in block-tile coordinates
    // D layout (verified): col = lane&31, row = (v&3) + 8*(v>>2) + 4*(lane>>5)
#pragma unroll
    for (int rb = 0; rb < 2; ++rb)
#pragma unroll
        for (int cb = 0; cb < 2; ++cb) {
            const int col   = wc * 64 + cb * 32 + (lane & 31);
            const int rbase = wr * 64 + rb * 32 + 4 * (lane >> 5);
#pragma unroll
            for (int v = 0; v < 16; ++v) {
                const int r = rbase + (v & 3) + 8 * (v >> 2);
                tile[r * 128 + col] = acc[rb][cb][v];
            }
        }

    __syncthreads();

    // ---- streaming (non-temporal) store sweep: bypass L2/L3 allocation.
    const f32x4* t4 = (const f32x4*)tile;
    float* Cbase = Cb + (size_t)brow * N2 + bcol;
#pragma unroll
    for (int it = 0; it < 16; ++it) {
        const int f  = it * 256 + threadIdx.x;   // float4 index in tile
        const int r  = f >> 5;                   // 32 float4 per 128-col row
        const int cq = f & 31;
        __builtin_nontemporal_store(t4[f], (f32x4*)(Cbase + (size_t)r * N2 + cq * 4));
    }
}

extern "C" void kernel_launch(void* const* d_in, const int* in_sizes, int n_in,
                              void* d_out, int out_size, void* d_ws, size_t ws_size,
                              hipStream_t stream) {
    const float* m1 = (const float*)d_in[0];
    const float* m2 = (const float*)d_in[1];
    float* out = (float*)d_out;

    const int N1 = 4096, N2 = 4096, D = 64;
    dim3 grid(N2 / 128, N1 / 128, 8);
    dim3 block(256);
    MatrixAttention_76149770158251_kernel<<<grid, block, 0, stream>>>(m1, m2, out, N1, N2, D);
}